// Round 1
// baseline (427.415 us; speedup 1.0000x reference)
//
#include <hip/hip_runtime.h>
#include <math.h>

// SphericalExpansion: per-edge 128-vector scatter-add into [N_ATOMS*N_SPECIES, 128].
// Round 0: coalesced atomic-scatter baseline.
//
// Inputs (setup_inputs order):
//   0: distances        [J]      f32
//   1: direction_vectors[J,3]    f32
//   2: radial_centers   [32]     f32   (index l*8+n)
//   3: z                [N_ATOMS] i32
//   4: idx_i            [J]      i32
//   5: idx_j            [J]      i32
// Output: ci [N_ATOMS,4,8,16] f32 flat = out[(idx_i*4 + z[idx_j])*128 + n*16 + lm]

__global__ __launch_bounds__(256) void sphexp_scatter(
    const float* __restrict__ dist,
    const float* __restrict__ dirs,
    const float* __restrict__ centers,
    const int*   __restrict__ zsp,
    const int*   __restrict__ idx_i,
    const int*   __restrict__ idx_j,
    float* __restrict__ out,
    int J)
{
    int tid = blockIdx.x * blockDim.x + threadIdx.x;
    int e = tid >> 7;          // edge index: 128 threads per edge
    int k = tid & 127;         // output slot: n = k>>4, lm = k&15
    if (e >= J) return;

    float r  = dist[e];
    float x  = dirs[3*e + 0];
    float y  = dirs[3*e + 1];
    float zc = dirs[3*e + 2];
    int rid  = zsp[idx_j[e]] + 4 * idx_i[e];

    int n  = k >> 4;
    int lm = k & 15;
    // l = floor(sqrt(lm)) for lm in [0,16): 0 | 1..3 | 4..8 | 9..15
    int l = (lm >= 9) ? 3 : (lm >= 4) ? 2 : (lm >= 1) ? 1 : 0;

    // radial basis: exp(-0.5*((r-c)/0.5)^2) = exp(-0.5*(2*(r-c))^2)
    float c  = centers[l * 8 + n];
    float t  = (r - c) * 2.0f;
    float rb = __expf(-0.5f * t * t);

    // shifted cosine cutoff: 1 for r<4.5, cosine decay on [4.5,5), 0 beyond
    float fc;
    if (r < 4.5f) {
        fc = 1.0f;
    } else {
        float u = (r - 4.5f) * 2.0f;       // (r - (rc-w))/w, w=0.5
        u = fminf(u, 1.0f);                 // clip; also covers r>=5 -> fc=0
        fc = 0.5f * (1.0f + __cosf(3.14159265358979f * u));
    }

    float x2 = x * x, y2 = y * y, z2 = zc * zc;
    float ylm;
    switch (lm) {
        case 0:  ylm = 0.28209479177387814f; break;
        case 1:  ylm = 0.4886025119029199f * y; break;
        case 2:  ylm = 0.4886025119029199f * zc; break;
        case 3:  ylm = 0.4886025119029199f * x; break;
        case 4:  ylm = 1.0925484305920792f * x * y; break;
        case 5:  ylm = 1.0925484305920792f * y * zc; break;
        case 6:  ylm = 0.31539156525252005f * (2.0f * z2 - x2 - y2); break;
        case 7:  ylm = 1.0925484305920792f * x * zc; break;
        case 8:  ylm = 0.5462742152960396f * (x2 - y2); break;
        case 9:  ylm = 0.5900435899266435f * y * (3.0f * x2 - y2); break;
        case 10: ylm = 2.890611442640554f * x * y * zc; break;
        case 11: ylm = 0.4570457994644658f * y * (4.0f * z2 - x2 - y2); break;
        case 12: ylm = 0.3731763325901154f * zc * (2.0f * z2 - 3.0f * x2 - 3.0f * y2); break;
        case 13: ylm = 0.4570457994644658f * x * (4.0f * z2 - x2 - y2); break;
        case 14: ylm = 1.445305721320277f * zc * (x2 - y2); break;
        default: ylm = 0.5900435899266435f * x * (x2 - 3.0f * y2); break;
    }

    float val = rb * fc * ylm;
    atomicAdd(out + (size_t)rid * 128 + k, val);
}

extern "C" void kernel_launch(void* const* d_in, const int* in_sizes, int n_in,
                              void* d_out, int out_size, void* d_ws, size_t ws_size,
                              hipStream_t stream) {
    const float* dist    = (const float*)d_in[0];
    const float* dirs    = (const float*)d_in[1];
    const float* centers = (const float*)d_in[2];
    const int*   zsp     = (const int*)d_in[3];
    const int*   idx_i   = (const int*)d_in[4];
    const int*   idx_j   = (const int*)d_in[5];
    float* out = (float*)d_out;
    int J = in_sizes[0];

    // harness poisons d_out with 0xAA before every timed launch -> zero it here
    hipMemsetAsync(d_out, 0, (size_t)out_size * sizeof(float), stream);

    long long total = (long long)J * 128;
    int block = 256;
    int grid  = (int)((total + block - 1) / block);
    sphexp_scatter<<<grid, block, 0, stream>>>(dist, dirs, centers, zsp, idx_i, idx_j, out, J);
}

// Round 2
// 404.334 us; speedup vs baseline: 1.0571x; 1.0571x over previous
//
#include <hip/hip_runtime.h>
#include <math.h>

// SphericalExpansion round 2: 16 threads/edge, branchless Ylm via LDS coeff table,
// coalesced f32 atomic scatter into out[(idx_i*4 + z[idx_j])*128 + n*16 + lm].
//
// Monomial basis order (20): 1, x, y, z, xx, yy, zz, xy, xz, yz,
//                            xxx, xxy, xxz, xyy, xyz, xzz, yyy, yyz, yzz, zzz

__constant__ float YCOEF[16 * 20] = {
    // lm0: 0.28209479*1
    0.28209479177387814f,0,0,0, 0,0,0,0, 0,0, 0,0,0,0, 0,0,0,0, 0,0,
    // lm1: 0.48860251*y
    0,0,0.4886025119029199f,0, 0,0,0,0, 0,0, 0,0,0,0, 0,0,0,0, 0,0,
    // lm2: 0.48860251*z
    0,0,0,0.4886025119029199f, 0,0,0,0, 0,0, 0,0,0,0, 0,0,0,0, 0,0,
    // lm3: 0.48860251*x
    0,0.4886025119029199f,0,0, 0,0,0,0, 0,0, 0,0,0,0, 0,0,0,0, 0,0,
    // lm4: 1.09254843*xy
    0,0,0,0, 0,0,0,1.0925484305920792f, 0,0, 0,0,0,0, 0,0,0,0, 0,0,
    // lm5: 1.09254843*yz
    0,0,0,0, 0,0,0,0, 0,1.0925484305920792f, 0,0,0,0, 0,0,0,0, 0,0,
    // lm6: 0.31539157*(2zz - xx - yy)
    0,0,0,0, -0.31539156525252005f,-0.31539156525252005f,0.6307831305050401f,0, 0,0, 0,0,0,0, 0,0,0,0, 0,0,
    // lm7: 1.09254843*xz
    0,0,0,0, 0,0,0,0, 1.0925484305920792f,0, 0,0,0,0, 0,0,0,0, 0,0,
    // lm8: 0.54627422*(xx - yy)
    0,0,0,0, 0.5462742152960396f,-0.5462742152960396f,0,0, 0,0, 0,0,0,0, 0,0,0,0, 0,0,
    // lm9: 0.59004359*y*(3xx - yy) = 1.77013077*xxy - 0.59004359*yyy
    0,0,0,0, 0,0,0,0, 0,0, 0,1.7701307697799305f,0,0, 0,0,-0.5900435899266435f,0, 0,0,
    // lm10: 2.89061144*xyz
    0,0,0,0, 0,0,0,0, 0,0, 0,0,0,0, 2.890611442640554f,0,0,0, 0,0,
    // lm11: 0.45704580*y*(4zz - xx - yy) = 1.82818320*yzz - 0.45704580*xxy - 0.45704580*yyy
    0,0,0,0, 0,0,0,0, 0,0, 0,-0.4570457994644658f,0,0, 0,0,-0.4570457994644658f,0, 1.8281831978578632f,0,
    // lm12: 0.37317633*z*(2zz - 3xx - 3yy) = 0.74635267*zzz - 1.11952900*xxz - 1.11952900*yyz
    0,0,0,0, 0,0,0,0, 0,0, 0,0,-1.1195289977703462f,0, 0,0,0,-1.1195289977703462f, 0,0.7463526651802308f,
    // lm13: 0.45704580*x*(4zz - xx - yy) = 1.82818320*xzz - 0.45704580*xxx - 0.45704580*xyy
    0,0,0,0, 0,0,0,0, 0,0, -0.4570457994644658f,0,0,-0.4570457994644658f, 0,1.8281831978578632f,0,0, 0,0,
    // lm14: 1.44530572*(xxz - yyz)
    0,0,0,0, 0,0,0,0, 0,0, 0,0,1.445305721320277f,0, 0,0,0,-1.445305721320277f, 0,0,
    // lm15: 0.59004359*x*(xx - 3yy) = 0.59004359*xxx - 1.77013077*xyy
    0,0,0,0, 0,0,0,0, 0,0, 0.5900435899266435f,0,0,-1.7701307697799305f, 0,0,0,0, 0,0,
};

__global__ __launch_bounds__(256) void sphexp16(
    const float* __restrict__ dist,
    const float* __restrict__ dirs,
    const float* __restrict__ centers,
    const int*   __restrict__ zsp,
    const int*   __restrict__ idx_i,
    const int*   __restrict__ idx_j,
    float* __restrict__ out,
    int J)
{
    __shared__ float sC[16 * 20];   // ylm coeff table
    __shared__ float sCen[32];      // radial centers [l*8+n]

    for (int i = threadIdx.x; i < 16 * 20 + 32; i += 256) {
        if (i < 320) sC[i] = YCOEF[i];
        else         sCen[i - 320] = centers[i - 320];
    }
    __syncthreads();

    int tid = blockIdx.x * 256 + threadIdx.x;
    int e = tid >> 4;     // edge: 16 threads per edge
    int t = tid & 15;     // lm index
    if (e >= J) return;

    float r = dist[e];
    float x = dirs[3 * e + 0];
    float y = dirs[3 * e + 1];
    float z = dirs[3 * e + 2];
    int rid = zsp[idx_j[e]] + 4 * idx_i[e];
    size_t base = (size_t)rid * 128 + t;

    // monomials
    float xx = x * x, yy = y * y, zz = z * z;
    float xy = x * y, xz = x * z, yz = y * z;
    float xxx = xx * x, xxy = xx * y, xxz = xx * z;
    float xyy = x * yy, xyz = xy * z, xzz = x * zz;
    float yyy = yy * y, yyz = yy * z, yzz = y * zz, zzz = zz * z;

    // branchless ylm: dense dot against row t (5x ds_read_b128)
    const float4* row = (const float4*)(&sC[t * 20]);
    float4 c0 = row[0], c1 = row[1], c2 = row[2], c3 = row[3], c4 = row[4];
    float ylm = c0.x
              + c0.y * x   + c0.z * y   + c0.w * z
              + c1.x * xx  + c1.y * yy  + c1.z * zz  + c1.w * xy
              + c2.x * xz  + c2.y * yz  + c2.z * xxx + c2.w * xxy
              + c3.x * xxz + c3.y * xyy + c3.z * xyz + c3.w * xzz
              + c4.x * yyy + c4.y * yyz + c4.z * yzz + c4.w * zzz;

    // branchless shifted cosine cutoff (r<4.5 -> u=0 -> fc=1; r>=5 -> u=1 -> fc=0)
    float u = fminf(fmaxf((r - 4.5f) * 2.0f, 0.0f), 1.0f);
    float fc = 0.5f * (1.0f + __cosf(3.14159265358979f * u));

    // l = 0 | 1..3 | 4..8 | 9..15
    int l = (t >= 9) ? 3 : (t >= 4) ? 2 : (t >= 1) ? 1 : 0;
    int lbase = l * 8;

    float pref = fc * ylm;
#pragma unroll
    for (int n = 0; n < 8; n++) {
        float d = (r - sCen[lbase + n]) * 2.0f;
        float v = pref * __expf(-0.5f * d * d);
        atomicAdd(out + base + (size_t)(n * 16), v);
    }
}

extern "C" void kernel_launch(void* const* d_in, const int* in_sizes, int n_in,
                              void* d_out, int out_size, void* d_ws, size_t ws_size,
                              hipStream_t stream) {
    const float* dist    = (const float*)d_in[0];
    const float* dirs    = (const float*)d_in[1];
    const float* centers = (const float*)d_in[2];
    const int*   zsp     = (const int*)d_in[3];
    const int*   idx_i   = (const int*)d_in[4];
    const int*   idx_j   = (const int*)d_in[5];
    float* out = (float*)d_out;
    int J = in_sizes[0];

    hipMemsetAsync(d_out, 0, (size_t)out_size * sizeof(float), stream);

    long long total = (long long)J * 16;
    int block = 256;
    int grid  = (int)((total + block - 1) / block);
    sphexp16<<<grid, block, 0, stream>>>(dist, dirs, centers, zsp, idx_i, idx_j, out, J);
}

// Round 3
// 259.175 us; speedup vs baseline: 1.6491x; 1.5601x over previous
//
#include <hip/hip_runtime.h>
#include <math.h>

// SphericalExpansion round 3: counting-sort by rid + per-row wave gather.
// Replaces 102.4M f32 atomics (TCC rate-limited, ~320us floor) with:
//   1. histogram of rid = z[idx_j] + 4*idx_i          (800k atomics, L2-resident)
//   2. exclusive scan over 80000 counters              (3 tiny kernels)
//   3. counting-sort scatter of edge ids               (800k atomics + stores)
//   4. gather: one wave per row, register accumulation, single coalesced write
// Output zeroing is implicit: every row is written exactly once by its wave.

#define NSPEC 4

// Monomial order (20): 1, x, y, z, xx, yy, zz, xy, xz, yz,
//                      xxx, xxy, xxz, xyy, xyz, xzz, yyy, yyz, yzz, zzz
__constant__ float YCOEF[16 * 20] = {
    0.28209479177387814f,0,0,0, 0,0,0,0, 0,0, 0,0,0,0, 0,0,0,0, 0,0,
    0,0,0.4886025119029199f,0, 0,0,0,0, 0,0, 0,0,0,0, 0,0,0,0, 0,0,
    0,0,0,0.4886025119029199f, 0,0,0,0, 0,0, 0,0,0,0, 0,0,0,0, 0,0,
    0,0.4886025119029199f,0,0, 0,0,0,0, 0,0, 0,0,0,0, 0,0,0,0, 0,0,
    0,0,0,0, 0,0,0,1.0925484305920792f, 0,0, 0,0,0,0, 0,0,0,0, 0,0,
    0,0,0,0, 0,0,0,0, 0,1.0925484305920792f, 0,0,0,0, 0,0,0,0, 0,0,
    0,0,0,0, -0.31539156525252005f,-0.31539156525252005f,0.6307831305050401f,0, 0,0, 0,0,0,0, 0,0,0,0, 0,0,
    0,0,0,0, 0,0,0,0, 1.0925484305920792f,0, 0,0,0,0, 0,0,0,0, 0,0,
    0,0,0,0, 0.5462742152960396f,-0.5462742152960396f,0,0, 0,0, 0,0,0,0, 0,0,0,0, 0,0,
    0,0,0,0, 0,0,0,0, 0,0, 0,1.7701307697799305f,0,0, 0,0,-0.5900435899266435f,0, 0,0,
    0,0,0,0, 0,0,0,0, 0,0, 0,0,0,0, 2.890611442640554f,0,0,0, 0,0,
    0,0,0,0, 0,0,0,0, 0,0, 0,-0.4570457994644658f,0,0, 0,0,-0.4570457994644658f,0, 1.8281831978578632f,0,
    0,0,0,0, 0,0,0,0, 0,0, 0,0,-1.1195289977703462f,0, 0,0,0,-1.1195289977703462f, 0,0.7463526651802308f,
    0,0,0,0, 0,0,0,0, 0,0, -0.4570457994644658f,0,0,-0.4570457994644658f, 0,1.8281831978578632f,0,0, 0,0,
    0,0,0,0, 0,0,0,0, 0,0, 0,0,1.445305721320277f,0, 0,0,0,-1.445305721320277f, 0,0,
    0,0,0,0, 0,0,0,0, 0,0, 0.5900435899266435f,0,0,-1.7701307697799305f, 0,0,0,0, 0,0,
};

__global__ __launch_bounds__(256) void k_hist(
    const int* __restrict__ zsp, const int* __restrict__ idx_i,
    const int* __restrict__ idx_j, int* __restrict__ rid_arr,
    int* __restrict__ counts, int J)
{
    int e = blockIdx.x * 256 + threadIdx.x;
    if (e >= J) return;
    int rid = zsp[idx_j[e]] + NSPEC * idx_i[e];
    rid_arr[e] = rid;
    atomicAdd(&counts[rid], 1);
}

__global__ __launch_bounds__(256) void k_scan1(
    const int* __restrict__ counts, int* __restrict__ offsets,
    int* __restrict__ bsums, int n)
{
    __shared__ int s[256];
    int i = blockIdx.x * 256 + threadIdx.x;
    int v = (i < n) ? counts[i] : 0;
    s[threadIdx.x] = v;
    __syncthreads();
    for (int off = 1; off < 256; off <<= 1) {
        int t = (threadIdx.x >= off) ? s[threadIdx.x - off] : 0;
        __syncthreads();
        s[threadIdx.x] += t;
        __syncthreads();
    }
    if (i < n) offsets[i] = s[threadIdx.x] - v;   // block-local exclusive
    if (threadIdx.x == 255) bsums[blockIdx.x] = s[255];
}

__global__ __launch_bounds__(512) void k_scan2(int* __restrict__ bsums, int nb)
{
    __shared__ int s[512];
    int t = threadIdx.x;
    int v = (t < nb) ? bsums[t] : 0;
    s[t] = v;
    __syncthreads();
    for (int off = 1; off < 512; off <<= 1) {
        int u = (t >= off) ? s[t - off] : 0;
        __syncthreads();
        s[t] += u;
        __syncthreads();
    }
    if (t < nb) bsums[t] = s[t] - v;               // exclusive
}

__global__ __launch_bounds__(256) void k_scan3(
    int* __restrict__ offsets, const int* __restrict__ bsums,
    int* __restrict__ cursor, int n, int total)
{
    int i = blockIdx.x * 256 + threadIdx.x;
    if (i < n) {
        int o = offsets[i] + bsums[blockIdx.x];
        offsets[i] = o;
        cursor[i]  = o;
    }
    if (i == 0) offsets[n] = total;
}

__global__ __launch_bounds__(256) void k_scatter(
    const int* __restrict__ rid_arr, int* __restrict__ cursor,
    int* __restrict__ sorted, int J)
{
    int e = blockIdx.x * 256 + threadIdx.x;
    if (e >= J) return;
    int pos = atomicAdd(&cursor[rid_arr[e]], 1);
    sorted[pos] = e;
}

// One 64-lane wave per output row. lane: lm = lane&15, n in {lane>>4, lane>>4+4}.
__global__ __launch_bounds__(256) void k_gather(
    const float* __restrict__ dist, const float* __restrict__ dirs,
    const float* __restrict__ centers, const int* __restrict__ offsets,
    const int* __restrict__ sorted, float* __restrict__ out, int nrows)
{
    int wid  = (blockIdx.x * 256 + threadIdx.x) >> 6;
    int lane = threadIdx.x & 63;
    int row  = __builtin_amdgcn_readfirstlane(wid);   // wave-uniform -> scalar path
    if (row >= nrows) return;

    int lm = lane & 15;
    int np = lane >> 4;                                // 0..3
    int l  = (lm >= 9) ? 3 : (lm >= 4) ? 2 : (lm >= 1) ? 1 : 0;
    float cen0 = centers[l * 8 + np];
    float cen1 = centers[l * 8 + np + 4];

    const float* cr = &YCOEF[lm * 20];
    float k0=cr[0],k1=cr[1],k2=cr[2],k3=cr[3],k4=cr[4],k5=cr[5],k6=cr[6],
          k7=cr[7],k8=cr[8],k9=cr[9],k10=cr[10],k11=cr[11],k12=cr[12],
          k13=cr[13],k14=cr[14],k15=cr[15],k16=cr[16],k17=cr[17],k18=cr[18],
          k19=cr[19];

    int beg = offsets[row];
    int end = offsets[row + 1];
    float a0 = 0.0f, a1 = 0.0f;

    for (int i = beg; i < end; ++i) {
        int eid = sorted[i];                           // wave-uniform (scalar load)
        float r = dist[eid];
        float x = dirs[3 * eid + 0];
        float y = dirs[3 * eid + 1];
        float z = dirs[3 * eid + 2];

        float xx = x*x, yy = y*y, zz = z*z;
        float ylm = k0
                  + k1*x + k2*y + k3*z
                  + k4*xx + k5*yy + k6*zz + k7*(x*y)
                  + k8*(x*z) + k9*(y*z)
                  + k10*(xx*x) + k11*(xx*y) + k12*(xx*z)
                  + k13*(x*yy) + k14*(x*y*z) + k15*(x*zz)
                  + k16*(yy*y) + k17*(yy*z) + k18*(y*zz) + k19*(zz*z);

        float u  = fminf(fmaxf((r - 4.5f) * 2.0f, 0.0f), 1.0f);
        float fc = 0.5f * (1.0f + __cosf(3.14159265358979f * u));
        float p  = fc * ylm;

        float d0 = (r - cen0) * 2.0f;
        float d1 = (r - cen1) * 2.0f;
        a0 += p * __expf(-0.5f * d0 * d0);
        a1 += p * __expf(-0.5f * d1 * d1);
    }

    size_t base = (size_t)row * 128;
    out[base + lane]      = a0;   // np*16 + lm == lane
    out[base + lane + 64] = a1;   // (np+4)*16 + lm == lane + 64
}

// Round-2 fallback (atomic scatter) in case ws is too small.
__global__ __launch_bounds__(256) void sphexp16_fb(
    const float* __restrict__ dist, const float* __restrict__ dirs,
    const float* __restrict__ centers, const int* __restrict__ zsp,
    const int* __restrict__ idx_i, const int* __restrict__ idx_j,
    float* __restrict__ out, int J)
{
    int tid = blockIdx.x * 256 + threadIdx.x;
    int e = tid >> 4, t = tid & 15;
    if (e >= J) return;
    float r = dist[e];
    float x = dirs[3*e], y = dirs[3*e+1], z = dirs[3*e+2];
    int rid = zsp[idx_j[e]] + NSPEC * idx_i[e];
    size_t base = (size_t)rid * 128 + t;
    const float* cr = &YCOEF[t * 20];
    float xx=x*x, yy=y*y, zz=z*z;
    float ylm = cr[0] + cr[1]*x + cr[2]*y + cr[3]*z
              + cr[4]*xx + cr[5]*yy + cr[6]*zz + cr[7]*(x*y)
              + cr[8]*(x*z) + cr[9]*(y*z)
              + cr[10]*(xx*x) + cr[11]*(xx*y) + cr[12]*(xx*z)
              + cr[13]*(x*yy) + cr[14]*(x*y*z) + cr[15]*(x*zz)
              + cr[16]*(yy*y) + cr[17]*(yy*z) + cr[18]*(y*zz) + cr[19]*(zz*z);
    float u = fminf(fmaxf((r - 4.5f) * 2.0f, 0.0f), 1.0f);
    float fc = 0.5f * (1.0f + __cosf(3.14159265358979f * u));
    int l = (t >= 9) ? 3 : (t >= 4) ? 2 : (t >= 1) ? 1 : 0;
    float pref = fc * ylm;
#pragma unroll
    for (int n = 0; n < 8; n++) {
        float d = (r - centers[l*8+n]) * 2.0f;
        atomicAdd(out + base + (size_t)(n*16), pref * __expf(-0.5f*d*d));
    }
}

extern "C" void kernel_launch(void* const* d_in, const int* in_sizes, int n_in,
                              void* d_out, int out_size, void* d_ws, size_t ws_size,
                              hipStream_t stream) {
    const float* dist    = (const float*)d_in[0];
    const float* dirs    = (const float*)d_in[1];
    const float* centers = (const float*)d_in[2];
    const int*   zsp     = (const int*)d_in[3];
    const int*   idx_i   = (const int*)d_in[4];
    const int*   idx_j   = (const int*)d_in[5];
    float* out = (float*)d_out;

    int J      = in_sizes[0];
    int natoms = in_sizes[3];
    int nrows  = natoms * NSPEC;

    // workspace layout (ints)
    size_t need = ((size_t)nrows          // counts
                 + (size_t)nrows + 1      // offsets
                 + (size_t)nrows          // cursor
                 + 512                    // block sums
                 + (size_t)J              // rid_arr
                 + (size_t)J) * 4;        // sorted
    if (ws_size < need) {
        hipMemsetAsync(d_out, 0, (size_t)out_size * sizeof(float), stream);
        long long total = (long long)J * 16;
        sphexp16_fb<<<(int)((total + 255) / 256), 256, 0, stream>>>(
            dist, dirs, centers, zsp, idx_i, idx_j, out, J);
        return;
    }

    int* counts  = (int*)d_ws;
    int* offsets = counts + nrows;
    int* cursor  = offsets + nrows + 1;
    int* bsums   = cursor + nrows;
    int* rid_arr = bsums + 512;
    int* sorted  = rid_arr + J;

    int nb1 = (nrows + 255) / 256;     // 313 for nrows=80000 (fits in 512)

    hipMemsetAsync(counts, 0, (size_t)nrows * sizeof(int), stream);
    k_hist<<<(J + 255) / 256, 256, 0, stream>>>(zsp, idx_i, idx_j, rid_arr, counts, J);
    k_scan1<<<nb1, 256, 0, stream>>>(counts, offsets, bsums, nrows);
    k_scan2<<<1, 512, 0, stream>>>(bsums, nb1);
    k_scan3<<<nb1, 256, 0, stream>>>(offsets, bsums, cursor, nrows, J);
    k_scatter<<<(J + 255) / 256, 256, 0, stream>>>(rid_arr, cursor, sorted, J);
    k_gather<<<(nrows * 64 + 255) / 256, 256, 0, stream>>>(
        dist, dirs, centers, offsets, sorted, out, nrows);
}